// Round 9
// baseline (169.107 us; speedup 1.0000x reference)
//
#include <hip/hip_runtime.h>
#include <hip/hip_bf16.h>

#define Bn 16
#define Cn 256
#define Tn 8192
#define TFn 512
#define HIDn 256
#define HEADSn 8
#define HDn 32
#define T2n (Tn/2)
#define TW 64
#define XPAD 264   // bf16 row stride: 528 B

// row-dependent column XOR swizzle (bf16 units): spreads the 4*row mod 32
// bank aliasing classes across 8 distinct 16B slots
#define XSWZ(row) ((((row) >> 3) & 7) << 3)

// ws float-index layout:
#define WS_G    0        // g[16][256]
#define WS_H    4096     // hh[16][256]
#define WS_QKB  8192     // qkb[16][8]
#define WS_QA   8320     // qA[16][8]
#define WS_QH   8448     // qH[16][8]
#define WS_AV   8576     // Av[16][256]
#define WS_BV   12672    // Bv[16][256]  (includes kv_b V-half)
#define WS_BF16 16768    // bf16 region start (float offset)
// bf16 element offsets within region:
#define BF_QKW2 0            // qkw2B[16][16][256]
#define BF_WV2  65536        // Wv2B[16][256][256]
#define BF_PROJ 1114112      // projB[256][256]

typedef __attribute__((ext_vector_type(8))) __bf16 bf16x8;
typedef __attribute__((ext_vector_type(4))) __bf16 bf16x4;
typedef __attribute__((ext_vector_type(4))) float f32x4;

// ---------------- prep1: per-batch scalars, g/hh, qkw2 (16 blocks) ----------
__global__ __launch_bounds__(256)
void prep1_kernel(const float* __restrict__ temb,
                  const float* __restrict__ ln_w, const float* __restrict__ ln_b,
                  const float* __restrict__ ss_w, const float* __restrict__ ss_b,
                  const float* __restrict__ kv_w, const float* __restrict__ kv_b,
                  const float* __restrict__ qw,  const float* __restrict__ qt_w,
                  const float* __restrict__ qt_b, float* __restrict__ ws)
{
    const int b = blockIdx.x, tid = threadIdx.x;
    __bf16* bfr = (__bf16*)(ws + WS_BF16);
    __shared__ float st[TFn];
    __shared__ float qbs[HIDn];
    __shared__ float gs[Cn], hs[Cn];
    __shared__ float pA[4][8], pH[4][8];

    for (int i = tid; i < TFn; i += 256) {
        float v = temb[b*TFn + i];
        st[i] = v / (1.f + __expf(-v));   // silu
    }
    __syncthreads();
    const float4* stv = (const float4*)st;
    const float4* wS = (const float4*)(ss_w + (size_t)tid*TFn);
    const float4* wC = (const float4*)(ss_w + (size_t)(Cn+tid)*TFn);
    const float4* wQ = (const float4*)(qt_w + (size_t)tid*TFn);
    float aS=0.f, aC=0.f, aQ=0.f;
    for (int k = 0; k < TFn/4; ++k) {
        float4 s = stv[k], a = wS[k], c = wC[k], q4 = wQ[k];
        aS += s.x*a.x + s.y*a.y + s.z*a.z + s.w*a.w;
        aC += s.x*c.x + s.y*c.y + s.z*c.z + s.w*c.w;
        aQ += s.x*q4.x + s.y*q4.y + s.z*q4.z + s.w*q4.w;
    }
    float shift = aS + ss_b[tid];
    float scale = aC + ss_b[Cn + tid];
    qbs[tid] = qw[tid] + aQ + qt_b[tid];
    float sc1 = 1.f + scale;
    float g = ln_w[tid] * sc1;
    float h = ln_b[tid] * sc1 + shift;
    gs[tid] = g; hs[tid] = h;
    ws[WS_G + b*Cn + tid] = g;
    ws[WS_H + b*Cn + tid] = h;
    __syncthreads();

    // qkw2B[b][h][c] = bf16(qkw[h][c]*g[c]); qA[h]=sum qkw*g; qH[h]=sum qkw*hh
    __bf16* qkw2B = bfr + BF_QKW2 + b*16*Cn;
    const int c = tid, wv = tid >> 6, ln = tid & 63;
    for (int hh2 = 0; hh2 < HEADSn; ++hh2) {
        float accq = 0.f;
        #pragma unroll
        for (int d = 0; d < HDn; ++d)
            accq += qbs[hh2*HDn + d] * kv_w[(size_t)(hh2*HDn + d)*Cn + c];
        float wg = accq * gs[c];
        float wh = accq * hs[c];
        qkw2B[hh2*Cn + c] = (__bf16)wg;
        float ra = wg, rh = wh;
        #pragma unroll
        for (int off = 1; off < 64; off <<= 1) {
            ra += __shfl_xor(ra, off);
            rh += __shfl_xor(rh, off);
        }
        if (ln == 0) { pA[wv][hh2] = ra; pH[wv][hh2] = rh; }
    }
    // zero pad rows 8..15
    for (int i = tid; i < 8*Cn; i += 256) qkw2B[8*Cn + i] = (__bf16)0.f;
    __syncthreads();
    if (tid < HEADSn) {
        ws[WS_QA + b*8 + tid] = pA[0][tid]+pA[1][tid]+pA[2][tid]+pA[3][tid];
        ws[WS_QH + b*8 + tid] = pH[0][tid]+pH[1][tid]+pH[2][tid]+pH[3][tid];
        float accb = 0.f;
        #pragma unroll
        for (int d = 0; d < HDn; ++d) accb += qbs[tid*HDn + d]*kv_b[tid*HDn + d];
        ws[WS_QKB + b*8 + tid] = accb;
    }
}

// ---------------- prep2: per-batch Wv2 + Av/Bv; projB conversion ------------
__global__ __launch_bounds__(256)
void prep2_kernel(const float* __restrict__ kv_w, const float* __restrict__ kv_b,
                  const float* __restrict__ proj_w, float* __restrict__ ws)
{
    const int tid = threadIdx.x, blk = blockIdx.x;
    __bf16* bfr = (__bf16*)(ws + WS_BF16);
    if (blk < 256) {
        int b  = blk >> 4, ch = blk & 15;
        int rr = tid >> 4, jj = tid & 15;
        int d  = ch*16 + rr;
        const float* gb = ws + WS_G + b*Cn;
        const float* hb = ws + WS_H + b*Cn;
        const float* wrow = kv_w + (size_t)(Cn + d)*Cn;   // V-half row
        __bf16* dst = bfr + BF_WV2 + (size_t)b*Cn*Cn + (size_t)d*Cn;
        float sa = 0.f, sb = 0.f;
        #pragma unroll
        for (int kk = 0; kk < 2; ++kk) {
            bf16x8 pk;
            #pragma unroll
            for (int j = 0; j < 8; ++j) {
                int cc = jj*16 + kk*8 + j;
                float v = wrow[cc], g = gb[cc];
                float vg = v*g;
                pk[j] = (__bf16)vg;
                sa += vg;
                sb += v*hb[cc];
            }
            *(bf16x8*)&dst[jj*16 + kk*8] = pk;
        }
        #pragma unroll
        for (int off = 1; off < 16; off <<= 1) {
            sa += __shfl_xor(sa, off);
            sb += __shfl_xor(sb, off);
        }
        if (jj == 0) {
            ws[WS_AV + b*Cn + d] = sa;
            ws[WS_BV + b*Cn + d] = sb + kv_b[Cn + d];
        }
    } else {
        // projB: 16 blocks x 256 thr x 16 elems
        size_t i0 = (size_t)(blk - 256)*4096 + (size_t)tid*16;
        #pragma unroll
        for (int kk = 0; kk < 2; ++kk) {
            bf16x8 pk;
            #pragma unroll
            for (int j = 0; j < 8; ++j) pk[j] = (__bf16)proj_w[i0 + kk*8 + j];
            *(bf16x8*)&bfr[BF_PROJ + i0 + kk*8] = pk;
        }
    }
}

// ---------------- main fused kernel ----------------------------------------
__global__ __launch_bounds__(256, 3)
void qna_main(const float* __restrict__ x, const float* __restrict__ rpe,
              const float* __restrict__ proj_b,
              const float* __restrict__ ws, float* __restrict__ out)
{
    __shared__ __bf16 xmT[TW][XPAD];     // raw-x bf16, col-XOR by XSWZ(t); reused as oT
    __shared__ float spool[512];         // red1/red2 (phase1) then aw[8][64] (phase3+)
    __shared__ float ivs[64], mivs[64];
    __shared__ float AvS[Cn], BvS[Cn], pbs[Cn];
    __shared__ float qAs[8], qHs[8], qkbs2[8];
    __shared__ float rpes[8][2];

    const int tid  = threadIdx.x;
    const int bt   = blockIdx.x;          // t-tile 0..127
    const int b    = blockIdx.y;
    const int lane = tid & 63;
    const int w    = tid >> 6;            // wave 0..3
    const int r    = lane & 15;
    const int qq   = lane >> 4;

    const __bf16* bfr   = (const __bf16*)(ws + WS_BF16);
    const __bf16* qkw2B = bfr + BF_QKW2 + b*16*Cn;
    const __bf16* Wv2B  = bfr + BF_WV2 + (size_t)b*Cn*Cn;
    const __bf16* projB = bfr + BF_PROJ;

    // ---- phase 0: per-batch params ----
    AvS[tid] = ws[WS_AV + b*Cn + tid];
    BvS[tid] = ws[WS_BV + b*Cn + tid];
    pbs[tid] = proj_b[tid];
    if (tid < 8) {
        qAs[tid]   = ws[WS_QA + b*8 + tid];
        qHs[tid]   = ws[WS_QH + b*8 + tid];
        qkbs2[tid] = ws[WS_QKB + b*8 + tid];
    }
    if (tid >= 16 && tid < 32) rpes[(tid-16)>>1][tid&1] = rpe[tid-16];

    // ---- phase 1: stream x once -> stats + raw bf16 to LDS ----
    const int t = lane;
    const float* xb = x + ((size_t)b*Cn + w*64)*Tn + (size_t)bt*TW + t;
    {
        float s = 0.f, sq = 0.f;
        for (int jb = 0; jb < 64; jb += 8) {
            float v[8];
            #pragma unroll
            for (int j = 0; j < 8; ++j) v[j] = xb[(size_t)(jb+j)*Tn];
            bf16x8 pk;
            #pragma unroll
            for (int j = 0; j < 8; ++j) {
                s += v[j]; sq += v[j]*v[j];
                pk[j] = (__bf16)v[j];
            }
            *(bf16x8*)&xmT[t][(w*64 + jb) ^ XSWZ(t)] = pk;
        }
        spool[w*64 + t] = s;
        spool[256 + w*64 + t] = sq;
    }
    __syncthreads();   // A

    // ---- phase 2a: stats reduce (tid<64) ----
    if (tid < 64) {
        float s  = spool[tid]     + spool[64+tid]  + spool[128+tid] + spool[192+tid];
        float sq = spool[256+tid] + spool[320+tid] + spool[384+tid] + spool[448+tid];
        float mean = s * (1.f/Cn);
        float var  = sq * (1.f/Cn) - mean*mean;
        float iv   = rsqrtf(var + 1e-6f);
        ivs[tid]  = iv;
        mivs[tid] = mean * iv;
    }

    // ---- phase 2b: logits MFMA on raw x ----
    f32x4 accL = {0.f,0.f,0.f,0.f};
    {
        const int tw = w*16 + r;
        #pragma unroll
        for (int k0 = 0; k0 < 8; ++k0) {
            bf16x8 a  = *(const bf16x8*)&qkw2B[(size_t)r*Cn + k0*32 + qq*8];
            bf16x8 bbv = *(const bf16x8*)&xmT[tw][(k0*32 + qq*8) ^ XSWZ(tw)];
            accL = __builtin_amdgcn_mfma_f32_16x16x32_bf16(a, bbv, accL, 0, 0, 0);
        }
    }

    // ---- phase 2c: V-GEMM MFMA on raw x. wave w owns d-rows [64w,64w+64) ----
    f32x4 acc[4][4];
    #pragma unroll
    for (int m = 0; m < 4; ++m)
        #pragma unroll
        for (int n = 0; n < 4; ++n) acc[m][n] = (f32x4){0.f,0.f,0.f,0.f};
    const int d0 = w*64;
    #pragma unroll
    for (int k0 = 0; k0 < 8; ++k0) {
        bf16x8 bb[4];
        #pragma unroll
        for (int n = 0; n < 4; ++n) {
            const int row = n*16 + r;
            bb[n] = *(const bf16x8*)&xmT[row][(k0*32 + qq*8) ^ XSWZ(row)];
        }
        #pragma unroll
        for (int m = 0; m < 4; ++m) {
            bf16x8 a = *(const bf16x8*)&Wv2B[(size_t)(d0 + m*16 + r)*Cn + k0*32 + qq*8];
            #pragma unroll
            for (int n = 0; n < 4; ++n)
                acc[m][n] = __builtin_amdgcn_mfma_f32_16x16x32_bf16(a, bb[n], acc[m][n], 0, 0, 0);
        }
    }
    __syncthreads();   // B  (stats ready; xmT fully consumed)

    // ---- phase 3: in-register logit correction + pairwise softmax ----
    {
        const int tcol = w*16 + r;
        float iv = ivs[tcol], miv = mivs[tcol];
        const float sc = 0.17677669529663687f;   // 1/sqrt(32)
        #pragma unroll
        for (int rr = 0; rr < 4; ++rr) {
            int h  = (qq*4 + rr) & 7;            // qq>=2 lanes compute garbage, not stored
            float l = (accL[rr]*iv - miv*qAs[h] + qHs[h] + qkbs2[h])*sc + rpes[h][r&1];
            float mx = fmaxf(l, __shfl_xor(l, 1));
            float e  = __expf(l - mx);
            float sm = e + __shfl_xor(e, 1);
            float aval = e / sm;
            if (qq < 2) spool[(qq*4 + rr)*64 + tcol] = aval;   // aw[h][t]
        }
    }
    __syncthreads();   // C  (aw ready)

    // ---- phase 4: V-correct + attn combine + write bf16 oT (xmT region) ----
    __bf16* oTp = &xmT[0][0];     // oT[u][d], stride XPAD, u<32, no XOR
    {
        #pragma unroll
        for (int m = 0; m < 4; ++m) {
            int dbase = d0 + m*16 + qq*4;
            int h = dbase >> 5;
            float av4[4], bv4[4];
            #pragma unroll
            for (int rr = 0; rr < 4; ++rr) { av4[rr] = AvS[dbase+rr]; bv4[rr] = BvS[dbase+rr]; }
            #pragma unroll
            for (int n = 0; n < 4; ++n) {
                int tl = n*16 + r;
                float ivn = ivs[tl], mivn = mivs[tl];
                float a0 = spool[h*64 + (tl & ~1)], a1 = spool[h*64 + (tl | 1)];
                bf16x4 ov;
                #pragma unroll
                for (int rr = 0; rr < 4; ++rr) {
                    float v  = ivn*acc[m][n][rr] - mivn*av4[rr] + bv4[rr];
                    float vo = __shfl_xor(v, 1);
                    float o  = a0*v + a1*vo;          // valid on even lanes
                    ov[rr] = (__bf16)o;
                }
                if (!(r & 1)) {
                    int u = n*8 + (r >> 1);
                    *(bf16x4*)&oTp[(size_t)u*XPAD + dbase] = ov;
                }
            }
        }
    }
    __syncthreads();   // D

    // ---- phase 5: proj GEMM via MFMA ----
    f32x4 acc2[4][2];
    #pragma unroll
    for (int m = 0; m < 4; ++m) { acc2[m][0] = (f32x4){0.f,0.f,0.f,0.f};
                                  acc2[m][1] = (f32x4){0.f,0.f,0.f,0.f}; }
    #pragma unroll
    for (int k0 = 0; k0 < 8; ++k0) {
        bf16x8 bb[2];
        #pragma unroll
        for (int n2 = 0; n2 < 2; ++n2)
            bb[n2] = *(const bf16x8*)&oTp[(size_t)(n2*16 + r)*XPAD + k0*32 + qq*8];
        #pragma unroll
        for (int m = 0; m < 4; ++m) {
            bf16x8 a = *(const bf16x8*)&projB[(size_t)(d0 + m*16 + r)*Cn + k0*32 + qq*8];
            #pragma unroll
            for (int n2 = 0; n2 < 2; ++n2)
                acc2[m][n2] = __builtin_amdgcn_mfma_f32_16x16x32_bf16(a, bb[n2], acc2[m][n2], 0, 0, 0);
        }
    }

    // ---- epilogue: bias + nontemporal store fp32 (keep x resident in L3) ----
    {
        float* ob = out + (size_t)b*HIDn*T2n + (size_t)bt*32;
        #pragma unroll
        for (int m = 0; m < 4; ++m) {
            #pragma unroll
            for (int n2 = 0; n2 < 2; ++n2) {
                #pragma unroll
                for (int rr = 0; rr < 4; ++rr) {
                    int e = d0 + m*16 + qq*4 + rr;
                    float vst = acc2[m][n2][rr] + pbs[e];
                    __builtin_nontemporal_store(vst, &ob[(size_t)e*T2n + n2*16 + r]);
                }
            }
        }
    }
}

extern "C" void kernel_launch(void* const* d_in, const int* in_sizes, int n_in,
                              void* d_out, int out_size, void* d_ws, size_t ws_size,
                              hipStream_t stream) {
    (void)in_sizes; (void)n_in; (void)out_size; (void)ws_size;
    const float* x      = (const float*)d_in[0];
    const float* temb   = (const float*)d_in[1];
    const float* ln_w   = (const float*)d_in[2];
    const float* ln_b   = (const float*)d_in[3];
    const float* ss_w   = (const float*)d_in[4];
    const float* ss_b   = (const float*)d_in[5];
    const float* kv_w   = (const float*)d_in[6];
    const float* kv_b   = (const float*)d_in[7];
    const float* q      = (const float*)d_in[8];
    const float* qt_w   = (const float*)d_in[9];
    const float* qt_b   = (const float*)d_in[10];
    const float* rpe    = (const float*)d_in[11];
    const float* proj_w = (const float*)d_in[12];
    const float* proj_b = (const float*)d_in[13];
    float* ws  = (float*)d_ws;
    float* out = (float*)d_out;

    prep1_kernel<<<dim3(Bn), dim3(256), 0, stream>>>(
        temb, ln_w, ln_b, ss_w, ss_b, kv_w, kv_b, q, qt_w, qt_b, ws);
    prep2_kernel<<<dim3(272), dim3(256), 0, stream>>>(kv_w, kv_b, proj_w, ws);
    qna_main<<<dim3(Tn/TW, Bn), dim3(256), 0, stream>>>(x, rpe, proj_b, ws, out);
}

// Round 11
// 150.570 us; speedup vs baseline: 1.1231x; 1.1231x over previous
//
#include <hip/hip_runtime.h>
#include <hip/hip_bf16.h>

#define Bn 16
#define Cn 256
#define Tn 8192
#define TFn 512
#define HIDn 256
#define HEADSn 8
#define HDn 32
#define T2n (Tn/2)
#define TW 256          // t-columns per block
#define T2W 128         // t2 per block
#define XPAD 264        // bf16 row stride: 528 B

// row-dependent column XOR swizzle (bf16 units, 16B granularity)
#define XSWZ(row) ((((row) >> 3) & 7) << 3)

// ws float-index layout:
#define WS_G    0        // g[16][256]
#define WS_H    4096     // hh[16][256]
#define WS_QKB  8192     // qkb[16][8]
#define WS_QA   8320     // qA[16][8]
#define WS_QH   8448     // qH[16][8]
#define WS_AV   8576     // Av[16][256]
#define WS_BV   12672    // Bv[16][256]
#define WS_BF16 16768    // bf16 region start (float offset)
#define BF_QKW2 0            // qkw2B[16][16][256]
#define BF_WV2  65536        // Wv2B[16][256][256]
#define BF_PROJ 1114112      // projB[256][256]

typedef __attribute__((ext_vector_type(8))) __bf16 bf16x8;
typedef __attribute__((ext_vector_type(4))) __bf16 bf16x4;
typedef __attribute__((ext_vector_type(4))) float f32x4;

// ---------------- prep1: per-batch scalars, g/hh, qkw2 (16 blocks) ----------
__global__ __launch_bounds__(256)
void prep1_kernel(const float* __restrict__ temb,
                  const float* __restrict__ ln_w, const float* __restrict__ ln_b,
                  const float* __restrict__ ss_w, const float* __restrict__ ss_b,
                  const float* __restrict__ kv_w, const float* __restrict__ kv_b,
                  const float* __restrict__ qw,  const float* __restrict__ qt_w,
                  const float* __restrict__ qt_b, float* __restrict__ ws)
{
    const int b = blockIdx.x, tid = threadIdx.x;
    __bf16* bfr = (__bf16*)(ws + WS_BF16);
    __shared__ float st[TFn];
    __shared__ float qbs[HIDn];
    __shared__ float gs[Cn], hs[Cn];
    __shared__ float pA[4][8], pH[4][8];

    for (int i = tid; i < TFn; i += 256) {
        float v = temb[b*TFn + i];
        st[i] = v / (1.f + __expf(-v));   // silu
    }
    __syncthreads();
    const float4* stv = (const float4*)st;
    const float4* wS = (const float4*)(ss_w + (size_t)tid*TFn);
    const float4* wC = (const float4*)(ss_w + (size_t)(Cn+tid)*TFn);
    const float4* wQ = (const float4*)(qt_w + (size_t)tid*TFn);
    float aS=0.f, aC=0.f, aQ=0.f;
    for (int k = 0; k < TFn/4; ++k) {
        float4 s = stv[k], a = wS[k], c = wC[k], q4 = wQ[k];
        aS += s.x*a.x + s.y*a.y + s.z*a.z + s.w*a.w;
        aC += s.x*c.x + s.y*c.y + s.z*c.z + s.w*c.w;
        aQ += s.x*q4.x + s.y*q4.y + s.z*q4.z + s.w*q4.w;
    }
    float shift = aS + ss_b[tid];
    float scale = aC + ss_b[Cn + tid];
    qbs[tid] = qw[tid] + aQ + qt_b[tid];
    float sc1 = 1.f + scale;
    float g = ln_w[tid] * sc1;
    float h = ln_b[tid] * sc1 + shift;
    gs[tid] = g; hs[tid] = h;
    ws[WS_G + b*Cn + tid] = g;
    ws[WS_H + b*Cn + tid] = h;
    __syncthreads();

    __bf16* qkw2B = bfr + BF_QKW2 + b*16*Cn;
    const int c = tid, wv = tid >> 6, ln = tid & 63;
    for (int hh2 = 0; hh2 < HEADSn; ++hh2) {
        float accq = 0.f;
        #pragma unroll
        for (int d = 0; d < HDn; ++d)
            accq += qbs[hh2*HDn + d] * kv_w[(size_t)(hh2*HDn + d)*Cn + c];
        float wg = accq * gs[c];
        float wh = accq * hs[c];
        qkw2B[hh2*Cn + c] = (__bf16)wg;
        float ra = wg, rh = wh;
        #pragma unroll
        for (int off = 1; off < 64; off <<= 1) {
            ra += __shfl_xor(ra, off);
            rh += __shfl_xor(rh, off);
        }
        if (ln == 0) { pA[wv][hh2] = ra; pH[wv][hh2] = rh; }
    }
    for (int i = tid; i < 8*Cn; i += 256) qkw2B[8*Cn + i] = (__bf16)0.f;
    __syncthreads();
    if (tid < HEADSn) {
        ws[WS_QA + b*8 + tid] = pA[0][tid]+pA[1][tid]+pA[2][tid]+pA[3][tid];
        ws[WS_QH + b*8 + tid] = pH[0][tid]+pH[1][tid]+pH[2][tid]+pH[3][tid];
        float accb = 0.f;
        #pragma unroll
        for (int d = 0; d < HDn; ++d) accb += qbs[tid*HDn + d]*kv_b[tid*HDn + d];
        ws[WS_QKB + b*8 + tid] = accb;
    }
}

// ---------------- prep2: per-batch Wv2 + Av/Bv; projB conversion ------------
__global__ __launch_bounds__(256)
void prep2_kernel(const float* __restrict__ kv_w, const float* __restrict__ kv_b,
                  const float* __restrict__ proj_w, float* __restrict__ ws)
{
    const int tid = threadIdx.x, blk = blockIdx.x;
    __bf16* bfr = (__bf16*)(ws + WS_BF16);
    if (blk < 256) {
        int b  = blk >> 4, ch = blk & 15;
        int rr = tid >> 4, jj = tid & 15;
        int d  = ch*16 + rr;
        const float* gb = ws + WS_G + b*Cn;
        const float* hb = ws + WS_H + b*Cn;
        const float* wrow = kv_w + (size_t)(Cn + d)*Cn;
        __bf16* dst = bfr + BF_WV2 + (size_t)b*Cn*Cn + (size_t)d*Cn;
        float sa = 0.f, sb = 0.f;
        #pragma unroll
        for (int kk = 0; kk < 2; ++kk) {
            bf16x8 pk;
            #pragma unroll
            for (int j = 0; j < 8; ++j) {
                int cc = jj*16 + kk*8 + j;
                float v = wrow[cc], g = gb[cc];
                float vg = v*g;
                pk[j] = (__bf16)vg;
                sa += vg;
                sb += v*hb[cc];
            }
            *(bf16x8*)&dst[jj*16 + kk*8] = pk;
        }
        #pragma unroll
        for (int off = 1; off < 16; off <<= 1) {
            sa += __shfl_xor(sa, off);
            sb += __shfl_xor(sb, off);
        }
        if (jj == 0) {
            ws[WS_AV + b*Cn + d] = sa;
            ws[WS_BV + b*Cn + d] = sb + kv_b[Cn + d];
        }
    } else {
        size_t i0 = (size_t)(blk - 256)*4096 + (size_t)tid*16;
        #pragma unroll
        for (int kk = 0; kk < 2; ++kk) {
            bf16x8 pk;
            #pragma unroll
            for (int j = 0; j < 8; ++j) pk[j] = (__bf16)proj_w[i0 + kk*8 + j];
            *(bf16x8*)&bfr[BF_PROJ + i0 + kk*8] = pk;
        }
    }
}

// ---------------- main fused kernel: 512 thr, 256-t tile --------------------
__global__ __launch_bounds__(512, 2)
void qna_main(const float* __restrict__ x, const float* __restrict__ rpe,
              const float* __restrict__ proj_b,
              const float* __restrict__ ws, float* __restrict__ out)
{
    __shared__ __bf16 xmT[TW][XPAD];     // 135168 B; rows t, cols c (XSWZ); reused as oT[128][XPAD]
    __shared__ float spool[4096];        // 16 KB: stats partials; reused as aw[8][256]
    __shared__ float ivs[TW], mivs[TW];
    __shared__ float AvS[Cn], BvS[Cn], pbs[Cn];
    __shared__ float qAs[8], qHs[8], qkbs2[8];
    __shared__ float rpes[8][2];

    const int tid  = threadIdx.x;
    const int bt   = blockIdx.x;          // t-tile 0..31
    const int b    = blockIdx.y;
    const int lane = tid & 63;
    const int w    = tid >> 6;            // wave 0..7
    const int r    = lane & 15;
    const int qq   = lane >> 4;

    const __bf16* bfr   = (const __bf16*)(ws + WS_BF16);
    const __bf16* qkw2B = bfr + BF_QKW2 + b*16*Cn;
    const __bf16* Wv2B  = bfr + BF_WV2 + (size_t)b*Cn*Cn;
    const __bf16* projB = bfr + BF_PROJ;

    // ---- phase 0: per-batch params ----
    if (tid < 256) {
        AvS[tid] = ws[WS_AV + b*Cn + tid];
        BvS[tid] = ws[WS_BV + b*Cn + tid];
    } else {
        int t2 = tid - 256;
        pbs[t2] = proj_b[t2];
        if (t2 < 8) {
            qAs[t2]   = ws[WS_QA + b*8 + t2];
            qHs[t2]   = ws[WS_QH + b*8 + t2];
            qkbs2[t2] = ws[WS_QKB + b*8 + t2];
        }
        if (t2 >= 16 && t2 < 32) rpes[(t2-16)>>1][t2&1] = rpe[t2-16];
    }

    // ---- phase 1: load x (1KB-contiguous), stats, 4x4 transpose to LDS ----
    // wave w owns c-rows [32w, 32w+32); lane owns t = 4*lane .. 4*lane+3
    {
        const float* xrow = x + ((size_t)b*Cn + w*32)*Tn + (size_t)bt*TW;
        float4 s4 = {0,0,0,0}, q4 = {0,0,0,0};
        #pragma unroll
        for (int jg = 0; jg < 8; ++jg) {
            float4 v[4];
            #pragma unroll
            for (int i = 0; i < 4; ++i)
                v[i] = *(const float4*)&xrow[(size_t)(jg*4 + i)*Tn + 4*lane];
            #pragma unroll
            for (int i = 0; i < 4; ++i) {
                s4.x += v[i].x; s4.y += v[i].y; s4.z += v[i].z; s4.w += v[i].w;
                q4.x += v[i].x*v[i].x; q4.y += v[i].y*v[i].y;
                q4.z += v[i].z*v[i].z; q4.w += v[i].w*v[i].w;
            }
            const int c0 = w*32 + jg*4;
            #pragma unroll
            for (int i2 = 0; i2 < 4; ++i2) {
                int t = 4*lane + i2;
                bf16x4 pk;
                pk[0] = (__bf16)((const float*)&v[0])[i2];
                pk[1] = (__bf16)((const float*)&v[1])[i2];
                pk[2] = (__bf16)((const float*)&v[2])[i2];
                pk[3] = (__bf16)((const float*)&v[3])[i2];
                *(bf16x4*)&xmT[t][c0 ^ XSWZ(t)] = pk;
            }
        }
        // spool layout: comp*512 + w*64 + lane  (s: comps 0..3, q: 2048 + same)
        spool[0*512 + w*64 + lane] = s4.x;
        spool[1*512 + w*64 + lane] = s4.y;
        spool[2*512 + w*64 + lane] = s4.z;
        spool[3*512 + w*64 + lane] = s4.w;
        spool[2048 + 0*512 + w*64 + lane] = q4.x;
        spool[2048 + 1*512 + w*64 + lane] = q4.y;
        spool[2048 + 2*512 + w*64 + lane] = q4.z;
        spool[2048 + 3*512 + w*64 + lane] = q4.w;
    }
    __syncthreads();   // A: xmT + spool ready

    // ---- stats (tid<256), concurrent with MFMA phases of other waves ----
    if (tid < 256) {
        const int t = tid, comp = t & 3, lq = t >> 2;
        float s = 0.f, sq = 0.f;
        #pragma unroll
        for (int w2 = 0; w2 < 8; ++w2) {
            s  += spool[comp*512 + w2*64 + lq];
            sq += spool[2048 + comp*512 + w2*64 + lq];
        }
        float mean = s * (1.f/Cn);
        float var  = sq * (1.f/Cn) - mean*mean;
        float iv   = rsqrtf(var + 1e-6f);
        ivs[t]  = iv;
        mivs[t] = mean * iv;
    }

    // ---- phase 2: logits MFMA — wave w owns t-tiles 2w, 2w+1 ----
    f32x4 accL[2];
    #pragma unroll
    for (int u = 0; u < 2; ++u) {
        accL[u] = (f32x4){0.f,0.f,0.f,0.f};
        const int trow = (2*w + u)*16 + r;
        #pragma unroll
        for (int k0 = 0; k0 < 8; ++k0) {
            bf16x8 a  = *(const bf16x8*)&qkw2B[(size_t)r*Cn + k0*32 + qq*8];
            bf16x8 bbv = *(const bf16x8*)&xmT[trow][(k0*32 + qq*8) ^ XSWZ(trow)];
            accL[u] = __builtin_amdgcn_mfma_f32_16x16x32_bf16(a, bbv, accL[u], 0, 0, 0);
        }
    }

    // ---- phase 3: V-GEMM. wave w: d-rows [(w&3)*64, +64), t-half (w>>2)*128 ----
    const int d0 = (w & 3) * 64;
    const int tb = (w >> 2) * 128;
    f32x4 acc[4][8];
    #pragma unroll
    for (int m = 0; m < 4; ++m)
        #pragma unroll
        for (int n = 0; n < 8; ++n) acc[m][n] = (f32x4){0.f,0.f,0.f,0.f};
    #pragma unroll
    for (int k0 = 0; k0 < 8; ++k0) {
        bf16x8 bb[8];
        #pragma unroll
        for (int n = 0; n < 8; ++n) {
            const int row = tb + n*16 + r;
            bb[n] = *(const bf16x8*)&xmT[row][(k0*32 + qq*8) ^ XSWZ(row)];
        }
        #pragma unroll
        for (int m = 0; m < 4; ++m) {
            bf16x8 a = *(const bf16x8*)&Wv2B[(size_t)(d0 + m*16 + r)*Cn + k0*32 + qq*8];
            #pragma unroll
            for (int n = 0; n < 8; ++n)
                acc[m][n] = __builtin_amdgcn_mfma_f32_16x16x32_bf16(a, bb[n], acc[m][n], 0, 0, 0);
        }
    }
    __syncthreads();   // B: xmT consumed; ivs ready

    // ---- phase 4: logit correction + pairwise softmax -> aw (spool region) ----
    float* aw = spool;   // aw[h][t] = spool[h*256 + t]
    {
        const float sc = 0.17677669529663687f;   // 1/sqrt(32)
        #pragma unroll
        for (int u = 0; u < 2; ++u) {
            const int tcol = (2*w + u)*16 + r;
            float iv = ivs[tcol], miv = mivs[tcol];
            #pragma unroll
            for (int rr = 0; rr < 4; ++rr) {
                int h  = (qq*4 + rr) & 7;
                float l = (accL[u][rr]*iv - miv*qAs[h] + qHs[h] + qkbs2[h])*sc + rpes[h][r&1];
                float mx = fmaxf(l, __shfl_xor(l, 1));
                float e  = __expf(l - mx);
                float sm = e + __shfl_xor(e, 1);
                float aval = e / sm;
                if (qq < 2) aw[(qq*4 + rr)*256 + tcol] = aval;
            }
        }
    }
    __syncthreads();   // C: aw ready, xmT region free for oT

    // ---- phase 5: V-correct + attn combine -> bf16 oT[u][d] (xmT region) ----
    __bf16* oTp = &xmT[0][0];    // oT[u][d], stride XPAD, u < 128
    {
        #pragma unroll
        for (int m = 0; m < 4; ++m) {
            const int dbase = d0 + m*16 + qq*4;
            const int h = dbase >> 5;
            float av4[4], bv4[4];
            #pragma unroll
            for (int rr = 0; rr < 4; ++rr) { av4[rr] = AvS[dbase+rr]; bv4[rr] = BvS[dbase+rr]; }
            #pragma unroll
            for (int n = 0; n < 8; ++n) {
                const int tl = tb + n*16 + r;
                float ivn = ivs[tl], mivn = mivs[tl];
                float a0 = aw[h*256 + (tl & ~1)], a1 = aw[h*256 + (tl | 1)];
                bf16x4 ov;
                #pragma unroll
                for (int rr = 0; rr < 4; ++rr) {
                    float v  = ivn*acc[m][n][rr] - mivn*av4[rr] + bv4[rr];
                    float vo = __shfl_xor(v, 1);
                    float o  = a0*v + a1*vo;          // valid on even lanes
                    ov[rr] = (__bf16)o;
                }
                if (!(r & 1)) {
                    int u = (tb >> 1) + n*8 + (r >> 1);    // t2 within tile, 0..127
                    *(bf16x4*)&oTp[(size_t)u*XPAD + dbase] = ov;
                }
            }
        }
    }
    __syncthreads();   // D: oT ready

    // ---- phase 6: proj GEMM. wave w: e-rows [(w&3)*64,+64), t2-half (w>>2)*64 ----
    const int t2b = (w >> 2) * 64;
    f32x4 acc2[4][4];
    #pragma unroll
    for (int m = 0; m < 4; ++m)
        #pragma unroll
        for (int n = 0; n < 4; ++n) acc2[m][n] = (f32x4){0.f,0.f,0.f,0.f};
    #pragma unroll
    for (int k0 = 0; k0 < 8; ++k0) {
        bf16x8 bb2[4];
        #pragma unroll
        for (int n = 0; n < 4; ++n)
            bb2[n] = *(const bf16x8*)&oTp[(size_t)(t2b + n*16 + r)*XPAD + k0*32 + qq*8];
        #pragma unroll
        for (int m = 0; m < 4; ++m) {
            bf16x8 a = *(const bf16x8*)&projB[(size_t)(d0 + m*16 + r)*Cn + k0*32 + qq*8];
            #pragma unroll
            for (int n = 0; n < 4; ++n)
                acc2[m][n] = __builtin_amdgcn_mfma_f32_16x16x32_bf16(a, bb2[n], acc2[m][n], 0, 0, 0);
        }
    }

    // ---- epilogue: bias + store fp32 (full 64-B lines) ----
    {
        float* ob = out + (size_t)b*HIDn*T2n + (size_t)bt*T2W;
        #pragma unroll
        for (int m = 0; m < 4; ++m) {
            #pragma unroll
            for (int n = 0; n < 4; ++n) {
                #pragma unroll
                for (int rr = 0; rr < 4; ++rr) {
                    int e = d0 + m*16 + qq*4 + rr;
                    ob[(size_t)e*T2n + t2b + n*16 + r] = acc2[m][n][rr] + pbs[e];
                }
            }
        }
    }
}

extern "C" void kernel_launch(void* const* d_in, const int* in_sizes, int n_in,
                              void* d_out, int out_size, void* d_ws, size_t ws_size,
                              hipStream_t stream) {
    (void)in_sizes; (void)n_in; (void)out_size; (void)ws_size;
    const float* x      = (const float*)d_in[0];
    const float* temb   = (const float*)d_in[1];
    const float* ln_w   = (const float*)d_in[2];
    const float* ln_b   = (const float*)d_in[3];
    const float* ss_w   = (const float*)d_in[4];
    const float* ss_b   = (const float*)d_in[5];
    const float* kv_w   = (const float*)d_in[6];
    const float* kv_b   = (const float*)d_in[7];
    const float* q      = (const float*)d_in[8];
    const float* qt_w   = (const float*)d_in[9];
    const float* qt_b   = (const float*)d_in[10];
    const float* rpe    = (const float*)d_in[11];
    const float* proj_w = (const float*)d_in[12];
    const float* proj_b = (const float*)d_in[13];
    float* ws  = (float*)d_ws;
    float* out = (float*)d_out;

    prep1_kernel<<<dim3(Bn), dim3(256), 0, stream>>>(
        temb, ln_w, ln_b, ss_w, ss_b, kv_w, kv_b, q, qt_w, qt_b, ws);
    prep2_kernel<<<dim3(272), dim3(256), 0, stream>>>(kv_w, kv_b, proj_w, ws);
    qna_main<<<dim3(Tn/TW, Bn), dim3(512), 0, stream>>>(x, rpe, proj_b, ws, out);
}

// Round 12
// 128.771 us; speedup vs baseline: 1.3132x; 1.1693x over previous
//
#include <hip/hip_runtime.h>
#include <hip/hip_bf16.h>

#define Bn 16
#define Cn 256
#define Tn 8192
#define TFn 512
#define HIDn 256
#define HEADSn 8
#define HDn 32
#define T2n (Tn/2)
#define TW 128          // t-columns per block
#define T2W 64          // t2 per block
#define XPAD 264        // bf16 row stride: 528 B

// row-dependent column XOR swizzle (bf16 units, 16B granularity)
#define XSWZ(row) ((((row) >> 3) & 7) << 3)

// ws float-index layout:
#define WS_CS   0        // condShift[16][256] (incl ss_b)
#define WS_CC   4096     // condScale[16][256] (incl ss_b)
#define WS_CQ   8192     // condQ[16][256] (q + qt + qt_b)
#define WS_G    12288    // g[16][256]
#define WS_H    16384    // hh[16][256]
#define WS_QKB  20480    // qkb[16][8]
#define WS_QA   20608    // qA[16][8]
#define WS_QH   20736    // qH[16][8]
#define WS_AV   20864    // Av[16][256]
#define WS_BV   24960    // Bv[16][256]
#define WS_BF16 29056    // bf16 region start (float offset)
#define BF_QKW2 0            // qkw2B[16][16][256]
#define BF_WV2  65536        // Wv2B[16][256][256]
#define BF_PROJ 1114112      // projB[256][256]

typedef __attribute__((ext_vector_type(8))) __bf16 bf16x8;
typedef __attribute__((ext_vector_type(4))) __bf16 bf16x4;
typedef __attribute__((ext_vector_type(4))) float f32x4;

// ---------------- prepA: 768-row GEMV, wave-cooperative (12 x 16 blocks) ----
__global__ __launch_bounds__(256)
void prepA_kernel(const float* __restrict__ temb,
                  const float* __restrict__ ss_w, const float* __restrict__ ss_b,
                  const float* __restrict__ qt_w, const float* __restrict__ qt_b,
                  const float* __restrict__ qw, float* __restrict__ ws)
{
    const int p = blockIdx.x;            // 0..11 (row chunk of 64)
    const int b = blockIdx.y;
    const int tid = threadIdx.x, lane = tid & 63, w = tid >> 6;
    __shared__ float st[TFn];
    for (int i = tid; i < TFn; i += 256) {
        float v = temb[b*TFn + i];
        st[i] = v / (1.f + __expf(-v));   // silu
    }
    __syncthreads();
    float4 s1 = *(const float4*)&st[lane*8];
    float4 s2 = *(const float4*)&st[lane*8 + 4];
    for (int i = 0; i < 16; ++i) {
        int row = p*64 + w*16 + i;
        const float* W = (row < 2*Cn) ? (ss_w + (size_t)row*TFn)
                                      : (qt_w + (size_t)(row - 2*Cn)*TFn);
        float4 a = *(const float4*)&W[lane*8];
        float4 c = *(const float4*)&W[lane*8 + 4];
        float d = a.x*s1.x + a.y*s1.y + a.z*s1.z + a.w*s1.w
                + c.x*s2.x + c.y*s2.y + c.z*s2.z + c.w*s2.w;
        #pragma unroll
        for (int off = 1; off < 64; off <<= 1) d += __shfl_xor(d, off);
        if (lane == 0) {
            if (row < Cn)
                ws[WS_CS + b*Cn + row] = d + ss_b[row];
            else if (row < 2*Cn)
                ws[WS_CC + b*Cn + (row - Cn)] = d + ss_b[row];
            else
                ws[WS_CQ + b*Cn + (row - 2*Cn)] = d + qt_b[row - 2*Cn] + qw[row - 2*Cn];
        }
    }
}

// ---------------- prepB: g/h + qkw2 + qA/qH/qkb (16 blocks) -----------------
__global__ __launch_bounds__(256)
void prepB_kernel(const float* __restrict__ ln_w, const float* __restrict__ ln_b,
                  const float* __restrict__ kv_w, const float* __restrict__ kv_b,
                  float* __restrict__ ws)
{
    const int b = blockIdx.x, tid = threadIdx.x;
    __bf16* bfr = (__bf16*)(ws + WS_BF16);
    __shared__ float qbs[HIDn], gs[Cn], hs[Cn];
    __shared__ float pA[4][8], pH[4][8];
    const int c = tid, wv = tid >> 6, ln = tid & 63;

    float sc1 = 1.f + ws[WS_CC + b*Cn + c];
    float g = ln_w[c] * sc1;
    float h = ln_b[c] * sc1 + ws[WS_CS + b*Cn + c];
    gs[c] = g; hs[c] = h;
    ws[WS_G + b*Cn + c] = g;
    ws[WS_H + b*Cn + c] = h;
    qbs[c] = ws[WS_CQ + b*Cn + c];
    __syncthreads();

    __bf16* qkw2B = bfr + BF_QKW2 + b*16*Cn;
    for (int hh2 = 0; hh2 < HEADSn; ++hh2) {
        float accq = 0.f;
        #pragma unroll
        for (int d = 0; d < HDn; ++d)
            accq += qbs[hh2*HDn + d] * kv_w[(size_t)(hh2*HDn + d)*Cn + c];
        float wg = accq * gs[c];
        float wh = accq * hs[c];
        qkw2B[hh2*Cn + c] = (__bf16)wg;
        float ra = wg, rh = wh;
        #pragma unroll
        for (int off = 1; off < 64; off <<= 1) {
            ra += __shfl_xor(ra, off);
            rh += __shfl_xor(rh, off);
        }
        if (ln == 0) { pA[wv][hh2] = ra; pH[wv][hh2] = rh; }
    }
    for (int i = tid; i < 8*Cn; i += 256) qkw2B[8*Cn + i] = (__bf16)0.f;
    __syncthreads();
    if (tid < HEADSn) {
        ws[WS_QA + b*8 + tid] = pA[0][tid]+pA[1][tid]+pA[2][tid]+pA[3][tid];
        ws[WS_QH + b*8 + tid] = pH[0][tid]+pH[1][tid]+pH[2][tid]+pH[3][tid];
        float accb = 0.f;
        #pragma unroll
        for (int d = 0; d < HDn; ++d) accb += qbs[tid*HDn + d]*kv_b[tid*HDn + d];
        ws[WS_QKB + b*8 + tid] = accb;
    }
}

// ---------------- prep2: per-batch Wv2 + Av/Bv; projB conversion ------------
__global__ __launch_bounds__(256)
void prep2_kernel(const float* __restrict__ kv_w, const float* __restrict__ kv_b,
                  const float* __restrict__ proj_w, float* __restrict__ ws)
{
    const int tid = threadIdx.x, blk = blockIdx.x;
    __bf16* bfr = (__bf16*)(ws + WS_BF16);
    if (blk < 256) {
        int b  = blk >> 4, ch = blk & 15;
        int rr = tid >> 4, jj = tid & 15;
        int d  = ch*16 + rr;
        const float* gb = ws + WS_G + b*Cn;
        const float* hb = ws + WS_H + b*Cn;
        const float* wrow = kv_w + (size_t)(Cn + d)*Cn;
        __bf16* dst = bfr + BF_WV2 + (size_t)b*Cn*Cn + (size_t)d*Cn;
        float sa = 0.f, sb = 0.f;
        #pragma unroll
        for (int kk = 0; kk < 2; ++kk) {
            bf16x8 pk;
            #pragma unroll
            for (int j = 0; j < 8; ++j) {
                int cc = jj*16 + kk*8 + j;
                float v = wrow[cc], g = gb[cc];
                float vg = v*g;
                pk[j] = (__bf16)vg;
                sa += vg;
                sb += v*hb[cc];
            }
            *(bf16x8*)&dst[jj*16 + kk*8] = pk;
        }
        #pragma unroll
        for (int off = 1; off < 16; off <<= 1) {
            sa += __shfl_xor(sa, off);
            sb += __shfl_xor(sb, off);
        }
        if (jj == 0) {
            ws[WS_AV + b*Cn + d] = sa;
            ws[WS_BV + b*Cn + d] = sb + kv_b[Cn + d];
        }
    } else {
        size_t i0 = (size_t)(blk - 256)*4096 + (size_t)tid*16;
        #pragma unroll
        for (int kk = 0; kk < 2; ++kk) {
            bf16x8 pk;
            #pragma unroll
            for (int j = 0; j < 8; ++j) pk[j] = (__bf16)proj_w[i0 + kk*8 + j];
            *(bf16x8*)&bfr[BF_PROJ + i0 + kk*8] = pk;
        }
    }
}

// ---------------- main fused kernel: 512 thr, 128-t tile, 2 blocks/CU -------
__global__ __launch_bounds__(512, 4)
void qna_main(const float* __restrict__ x, const float* __restrict__ rpe,
              const float* __restrict__ proj_b,
              const float* __restrict__ ws, float* __restrict__ out)
{
    __shared__ __bf16 xmT[TW][XPAD];     // 67584 B; rows t, cols c (XSWZ); reused as oT[64][XPAD]
    __shared__ float spool[2048];        // 8 KB: stats partials; reused as aw[8][128]
    __shared__ float ivs[TW], mivs[TW];
    __shared__ float AvS[Cn], BvS[Cn], pbs[Cn];
    __shared__ float qAs[8], qHs[8], qkbs2[8];
    __shared__ float rpes[8][2];

    const int tid  = threadIdx.x;
    const int bt   = blockIdx.x;          // t-tile 0..63
    const int b    = blockIdx.y;
    const int lane = tid & 63;
    const int w    = tid >> 6;            // wave 0..7
    const int r    = lane & 15;
    const int qq   = lane >> 4;

    const __bf16* bfr   = (const __bf16*)(ws + WS_BF16);
    const __bf16* qkw2B = bfr + BF_QKW2 + b*16*Cn;
    const __bf16* Wv2B  = bfr + BF_WV2 + (size_t)b*Cn*Cn;
    const __bf16* projB = bfr + BF_PROJ;

    // ---- phase 0: per-batch params ----
    if (tid < 256) {
        AvS[tid] = ws[WS_AV + b*Cn + tid];
        BvS[tid] = ws[WS_BV + b*Cn + tid];
    } else {
        int t2 = tid - 256;
        pbs[t2] = proj_b[t2];
        if (t2 < 8) {
            qAs[t2]   = ws[WS_QA + b*8 + t2];
            qHs[t2]   = ws[WS_QH + b*8 + t2];
            qkbs2[t2] = ws[WS_QKB + b*8 + t2];
        }
        if (t2 >= 16 && t2 < 32) rpes[(t2-16)>>1][t2&1] = rpe[t2-16];
    }

    // ---- phase 1: load x (512B-contig float2), stats, 4x2 transpose to LDS ----
    // wave w owns c-rows [32w, 32w+32); lane owns t = 2*lane, 2*lane+1
    {
        const float* xrow = x + ((size_t)b*Cn + w*32)*Tn + (size_t)bt*TW;
        const int t0 = 2*lane;
        float s0 = 0.f, s1 = 0.f, q0 = 0.f, q1 = 0.f;
        #pragma unroll
        for (int jg = 0; jg < 8; ++jg) {
            float2 v[4];
            #pragma unroll
            for (int i = 0; i < 4; ++i)
                v[i] = *(const float2*)&xrow[(size_t)(jg*4 + i)*Tn + t0];
            bf16x4 p0, p1;
            #pragma unroll
            for (int i = 0; i < 4; ++i) {
                s0 += v[i].x; q0 += v[i].x*v[i].x;
                s1 += v[i].y; q1 += v[i].y*v[i].y;
                p0[i] = (__bf16)v[i].x;
                p1[i] = (__bf16)v[i].y;
            }
            const int c0 = w*32 + jg*4;
            *(bf16x4*)&xmT[t0][c0 ^ XSWZ(t0)]     = p0;
            *(bf16x4*)&xmT[t0+1][c0 ^ XSWZ(t0+1)] = p1;
        }
        spool[w*128 + t0]       = s0;
        spool[w*128 + t0 + 1]   = s1;
        spool[1024 + w*128 + t0]     = q0;
        spool[1024 + w*128 + t0 + 1] = q1;
    }
    __syncthreads();   // A: xmT + spool ready

    // ---- stats reduce (tid<128) ----
    if (tid < TW) {
        const int t = tid;
        float s = 0.f, sq = 0.f;
        #pragma unroll
        for (int w2 = 0; w2 < 8; ++w2) {
            s  += spool[w2*128 + t];
            sq += spool[1024 + w2*128 + t];
        }
        float mean = s * (1.f/Cn);
        float var  = sq * (1.f/Cn) - mean*mean;
        float iv   = rsqrtf(var + 1e-6f);
        ivs[t]  = iv;
        mivs[t] = mean * iv;
    }

    // ---- phase 2: logits MFMA — wave w owns t-tile w ----
    f32x4 accL = {0.f,0.f,0.f,0.f};
    {
        const int trow = w*16 + r;
        #pragma unroll
        for (int k0 = 0; k0 < 8; ++k0) {
            bf16x8 a  = *(const bf16x8*)&qkw2B[(size_t)r*Cn + k0*32 + qq*8];
            bf16x8 bbv = *(const bf16x8*)&xmT[trow][(k0*32 + qq*8) ^ XSWZ(trow)];
            accL = __builtin_amdgcn_mfma_f32_16x16x32_bf16(a, bbv, accL, 0, 0, 0);
        }
    }

    // ---- phase 3: V-GEMM. wave w: d-rows [(w&3)*64,+64), t-half (w>>2)*64 ----
    const int d0 = (w & 3) * 64;
    const int tb = (w >> 2) * 64;
    f32x4 acc[4][4];
    #pragma unroll
    for (int m = 0; m < 4; ++m)
        #pragma unroll
        for (int n = 0; n < 4; ++n) acc[m][n] = (f32x4){0.f,0.f,0.f,0.f};
    #pragma unroll
    for (int k0 = 0; k0 < 8; ++k0) {
        bf16x8 bb[4];
        #pragma unroll
        for (int n = 0; n < 4; ++n) {
            const int row = tb + n*16 + r;
            bb[n] = *(const bf16x8*)&xmT[row][(k0*32 + qq*8) ^ XSWZ(row)];
        }
        #pragma unroll
        for (int m = 0; m < 4; ++m) {
            bf16x8 a = *(const bf16x8*)&Wv2B[(size_t)(d0 + m*16 + r)*Cn + k0*32 + qq*8];
            #pragma unroll
            for (int n = 0; n < 4; ++n)
                acc[m][n] = __builtin_amdgcn_mfma_f32_16x16x32_bf16(a, bb[n], acc[m][n], 0, 0, 0);
        }
    }
    __syncthreads();   // B: xmT consumed; spool(stats) consumed; ivs ready

    // ---- phase 4: logit correction + pairwise softmax -> aw (spool region) ----
    float* aw = spool;   // aw[h][t] = spool[h*128 + t]
    {
        const float sc = 0.17677669529663687f;   // 1/sqrt(32)
        const int tcol = w*16 + r;
        float iv = ivs[tcol], miv = mivs[tcol];
        #pragma unroll
        for (int rr = 0; rr < 4; ++rr) {
            int h  = (qq*4 + rr) & 7;
            float l = (accL[rr]*iv - miv*qAs[h] + qHs[h] + qkbs2[h])*sc + rpes[h][r&1];
            float mx = fmaxf(l, __shfl_xor(l, 1));
            float e  = __expf(l - mx);
            float sm = e + __shfl_xor(e, 1);
            float aval = e / sm;
            if (qq < 2) aw[(qq*4 + rr)*128 + tcol] = aval;
        }
    }
    __syncthreads();   // C: aw ready, xmT region free for oT

    // ---- phase 5: V-correct + attn combine -> bf16 oT[u][d] (xmT region) ----
    __bf16* oTp = &xmT[0][0];    // oT[u][d], stride XPAD, u < 64
    {
        #pragma unroll
        for (int m = 0; m < 4; ++m) {
            const int dbase = d0 + m*16 + qq*4;
            const int h = dbase >> 5;
            float av4[4], bv4[4];
            #pragma unroll
            for (int rr = 0; rr < 4; ++rr) { av4[rr] = AvS[dbase+rr]; bv4[rr] = BvS[dbase+rr]; }
            #pragma unroll
            for (int n = 0; n < 4; ++n) {
                const int tl = tb + n*16 + r;
                float ivn = ivs[tl], mivn = mivs[tl];
                float a0 = aw[h*128 + (tl & ~1)], a1 = aw[h*128 + (tl | 1)];
                bf16x4 ov;
                #pragma unroll
                for (int rr = 0; rr < 4; ++rr) {
                    float v  = ivn*acc[m][n][rr] - mivn*av4[rr] + bv4[rr];
                    float vo = __shfl_xor(v, 1);
                    float o  = a0*v + a1*vo;          // valid on even lanes
                    ov[rr] = (__bf16)o;
                }
                if (!(r & 1)) {
                    int u = (tb >> 1) + n*8 + (r >> 1);    // t2 within tile, 0..63
                    *(bf16x4*)&oTp[(size_t)u*XPAD + dbase] = ov;
                }
            }
        }
    }
    __syncthreads();   // D: oT ready

    // ---- phase 6: proj GEMM. wave w: e-rows [(w&3)*64,+64), t2-half (w>>2)*32 ----
    const int t2b = (w >> 2) * 32;
    f32x4 acc2[4][2];
    #pragma unroll
    for (int m = 0; m < 4; ++m) { acc2[m][0] = (f32x4){0.f,0.f,0.f,0.f};
                                  acc2[m][1] = (f32x4){0.f,0.f,0.f,0.f}; }
    #pragma unroll
    for (int k0 = 0; k0 < 8; ++k0) {
        bf16x8 bb2[2];
        #pragma unroll
        for (int n2 = 0; n2 < 2; ++n2)
            bb2[n2] = *(const bf16x8*)&oTp[(size_t)(t2b + n2*16 + r)*XPAD + k0*32 + qq*8];
        #pragma unroll
        for (int m = 0; m < 4; ++m) {
            bf16x8 a = *(const bf16x8*)&projB[(size_t)(d0 + m*16 + r)*Cn + k0*32 + qq*8];
            #pragma unroll
            for (int n2 = 0; n2 < 2; ++n2)
                acc2[m][n2] = __builtin_amdgcn_mfma_f32_16x16x32_bf16(a, bb2[n2], acc2[m][n2], 0, 0, 0);
        }
    }

    // ---- epilogue: bias + store fp32 ----
    {
        float* ob = out + (size_t)b*HIDn*T2n + (size_t)bt*T2W;
        #pragma unroll
        for (int m = 0; m < 4; ++m) {
            #pragma unroll
            for (int n2 = 0; n2 < 2; ++n2) {
                #pragma unroll
                for (int rr = 0; rr < 4; ++rr) {
                    int e = d0 + m*16 + qq*4 + rr;
                    ob[(size_t)e*T2n + t2b + n2*16 + r] = acc2[m][n2][rr] + pbs[e];
                }
            }
        }
    }
}

extern "C" void kernel_launch(void* const* d_in, const int* in_sizes, int n_in,
                              void* d_out, int out_size, void* d_ws, size_t ws_size,
                              hipStream_t stream) {
    (void)in_sizes; (void)n_in; (void)out_size; (void)ws_size;
    const float* x      = (const float*)d_in[0];
    const float* temb   = (const float*)d_in[1];
    const float* ln_w   = (const float*)d_in[2];
    const float* ln_b   = (const float*)d_in[3];
    const float* ss_w   = (const float*)d_in[4];
    const float* ss_b   = (const float*)d_in[5];
    const float* kv_w   = (const float*)d_in[6];
    const float* kv_b   = (const float*)d_in[7];
    const float* q      = (const float*)d_in[8];
    const float* qt_w   = (const float*)d_in[9];
    const float* qt_b   = (const float*)d_in[10];
    const float* rpe    = (const float*)d_in[11];
    const float* proj_w = (const float*)d_in[12];
    const float* proj_b = (const float*)d_in[13];
    float* ws  = (float*)d_ws;
    float* out = (float*)d_out;

    prepA_kernel<<<dim3(12, Bn), dim3(256), 0, stream>>>(
        temb, ss_w, ss_b, qt_w, qt_b, q, ws);
    prepB_kernel<<<dim3(Bn), dim3(256), 0, stream>>>(ln_w, ln_b, kv_w, kv_b, ws);
    prep2_kernel<<<dim3(272), dim3(256), 0, stream>>>(kv_w, kv_b, proj_w, ws);
    qna_main<<<dim3(Tn/TW, Bn), dim3(512), 0, stream>>>(x, rpe, proj_b, ws, out);
}